// Round 4
// baseline (403.444 us; speedup 1.0000x reference)
//
#include <hip/hip_runtime.h>
#include <hip/hip_bf16.h>

// ---------------------------------------------------------------------------
// Problem: N=25600 rows, D=640, B=64, H=10, dk=64, SEQ=400.  head_splitter is
// a RAW RESHAPE: head (b,h) owns flat range [bh*25600,+25600) == x-rows
// [bh*40,+40) x all 640 cols.  Qblk/Vblk = range viewed [400][64]; Kblk =
// same range viewed [64][400].  vals flat order == out flat order.
//
// R8.  R7 counters: attn 159us (Mfma 9.9, VALU 52, Occ 58, VGPR 32) ->
// per-block critical path ~6.4us of unoverlapped latency: B5 13 serial
// K-steps 1-deep, B3 5 serial rows x chained shfl trees, B6 cold x loads.
// qkv ~145us: 64 scalar u16 global stores/thread epilogue + no A-panel
// locality.  This round:
//   attn: B5 3-deep static ring; B3 all-5-rows interleaved reductions;
//         x loads hoisted to kernel top.  Same math order (absmax stable).
//   qkv : LDS repack epilogue (stride-144) -> 8 coalesced b128 stores;
//         XCD swizzle + A-panel-major grid order; 36KB dynamic LDS.
// ---------------------------------------------------------------------------

typedef unsigned short u16;
typedef short s8v __attribute__((ext_vector_type(8)));   // 8 bf16 (4 VGPRs)
typedef float f4v __attribute__((ext_vector_type(4)));   // MFMA accumulator
typedef u16  u4v __attribute__((ext_vector_type(4)));    // 4 bf16 (8B store)
typedef u16  u8v __attribute__((ext_vector_type(8)));    // 8 bf16 (16B store)

__device__ __forceinline__ float us2f(u16 u) {
    union { float f; unsigned int i; } v; v.i = ((unsigned int)u) << 16; return v.f;
}
__device__ __forceinline__ u16 f2us(float f) {
    __hip_bfloat16 h = __float2bfloat16(f);
    return *reinterpret_cast<u16*>(&h);
}
__device__ __forceinline__ s8v ld8f(const float* p) {   // 8 fp32 -> bf16x8
    const float4 a = ((const float4*)p)[0], b = ((const float4*)p)[1];
    s8v r;
    r[0] = (short)f2us(a.x); r[1] = (short)f2us(a.y);
    r[2] = (short)f2us(a.z); r[3] = (short)f2us(a.w);
    r[4] = (short)f2us(b.x); r[5] = (short)f2us(b.y);
    r[6] = (short)f2us(b.z); r[7] = (short)f2us(b.w);
    return r;
}
__device__ __forceinline__ void gload16(const u16* g, u16* l) {
    u16* gm = const_cast<u16*>(g);                       // builtin is non-const
    __builtin_amdgcn_global_load_lds(
        (__attribute__((address_space(1))) unsigned int*)gm,
        (__attribute__((address_space(3))) unsigned int*)l, 16, 0, 0);
}

// ============================ NEW PATH =====================================

// ---- cvt: W (3x640x640) and x (25600x640) fp32 -> bf16 --------------------
__global__ __launch_bounds__(256)
void cvt(const float* __restrict__ Wq, const float* __restrict__ Wk,
         const float* __restrict__ Wv, const float* __restrict__ x,
         u16* __restrict__ Wb, u16* __restrict__ xb)
{
    const int g = blockIdx.x * 256 + threadIdx.x;
    if (g < 153600) {
        const float* src = (g < 51200) ? Wq : (g < 102400) ? Wk : Wv;
        const int rem = g % 51200;
        *(s8v*)(Wb + (size_t)g * 8) = ld8f(src + (size_t)rem * 8);
    } else {
        const int gx = g - 153600;
        *(s8v*)(xb + (size_t)gx * 8) = ld8f(x + (size_t)gx * 8);
    }
}

// ---- qkv: [25600x640]bf16 @ Wb^T[1920x640]bf16 -> Q/K/V bf16 --------------
// 128x128 tile, BK=64, 256 thr (4 waves 2x2, 64x64 each, 4x4 acc).
// Staging via global_load_lds dwordx4, 16B-granule XOR swizzle.  Epilogue
// repacks C through LDS (row stride 144 u16) -> 8 coalesced b128 stores.
// Grid: XCD swizzle then A-panel-major (15 consecutive blocks per x-panel).
#define QKV_LDS 36864
__global__ __launch_bounds__(256, 4)
void qkv(const u16* __restrict__ xb, const u16* __restrict__ Wb,
         u16* __restrict__ Qb, u16* __restrict__ Kb, u16* __restrict__ Vb)
{
    extern __shared__ u16 qsm[];                // 36864 B
    u16* As = qsm;                              // [128][64] swizzled, 16KB
    u16* Bs = qsm + 8192;                       // [128][64] swizzled, 16KB
    const int bx = blockIdx.x;
    const int sw = (bx & 7) * 375 + (bx >> 3);  // XCD swizzle (3000 = 8*375)
    const int mt = sw / 15, nt = sw % 15;       // A-panel-major
    const int m0 = mt * 128, n0 = nt * 128;
    const int t = threadIdx.x, lane = t & 63, w = t >> 6;
    const int l15 = lane & 15, quad = lane >> 4;
    const int wr = w >> 1, wc = w & 1;

    f4v acc[4][4];
    #pragma unroll
    for (int a = 0; a < 4; ++a)
        #pragma unroll
        for (int b = 0; b < 4; ++b) acc[a][b] = (f4v){0.f, 0.f, 0.f, 0.f};

    for (int k0 = 0; k0 < 640; k0 += 64) {
        __syncthreads();                   // prev iter's frag reads done
        #pragma unroll
        for (int j = 0; j < 4; ++j) {
            const int c  = (w * 4 + j) * 64 + lane;      // linear 16B chunk
            const int rg = c >> 3;
            const int sg = (c & 7) ^ (rg & 7);           // inverse swizzle
            gload16(xb + (size_t)(m0 + rg) * 640 + k0 + sg * 8,
                    As + (w * 4 + j) * 512);
            gload16(Wb + (size_t)(n0 + rg) * 640 + k0 + sg * 8,
                    Bs + (w * 4 + j) * 512);
        }
        __syncthreads();                   // vmcnt(0) drained before barrier

        #pragma unroll
        for (int kk = 0; kk < 2; ++kk) {
            s8v af[4], bf[4];
            #pragma unroll
            for (int mi = 0; mi < 4; ++mi) {
                const int row = wr * 64 + mi * 16 + l15;
                const int s   = kk * 4 + quad;
                af[mi] = *(const s8v*)(As + ((row * 8 + (s ^ (row & 7))) << 3));
            }
            #pragma unroll
            for (int ni = 0; ni < 4; ++ni) {
                const int row = wc * 64 + ni * 16 + l15;
                const int s   = kk * 4 + quad;
                bf[ni] = *(const s8v*)(Bs + ((row * 8 + (s ^ (row & 7))) << 3));
            }
            #pragma unroll
            for (int mi = 0; mi < 4; ++mi)
                #pragma unroll
                for (int ni = 0; ni < 4; ++ni)
                    acc[mi][ni] = __builtin_amdgcn_mfma_f32_16x16x32_bf16(
                        af[mi], bf[ni], acc[mi][ni], 0, 0, 0);
        }
    }

    // epilogue: repack through LDS (stride 144 u16), then coalesced stores
    __syncthreads();                       // all frag reads done; reuse qsm
    u16* Cs = qsm;                         // [128][144] u16 = 36864 B
    #pragma unroll
    for (int mi = 0; mi < 4; ++mi)
        #pragma unroll
        for (int ni = 0; ni < 4; ++ni)
            #pragma unroll
            for (int i = 0; i < 4; ++i) {
                const int row = wr * 64 + mi * 16 + quad * 4 + i;
                const int col = wc * 64 + ni * 16 + l15;
                Cs[row * 144 + col] = f2us(acc[mi][ni][i]);
            }
    __syncthreads();
    const int mat = (n0 >= 1280) ? 2 : (n0 >= 640 ? 1 : 0);
    u16* dst = (mat == 0) ? Qb : (mat == 1 ? Kb : Vb);
    const int lc0 = n0 - mat * 640;
    #pragma unroll
    for (int j2 = 0; j2 < 8; ++j2) {
        const int cl  = t + 256 * j2;      // 0..2047 output 16B chunks
        const int row = cl >> 4, cg = cl & 15;
        const s8v v = *(const s8v*)(Cs + row * 144 + cg * 8);
        *(s8v*)(dst + (size_t)(m0 + row) * 640 + lc0 + cg * 8) = v;
    }
}

// ---- kvt: per-head transposes (640 blocks, one head each) -----------------
__global__ __launch_bounds__(256)
void kvt(const u16* __restrict__ Kb, const u16* __restrict__ Vb,
         u16* __restrict__ Ktg, u16* __restrict__ Vtg)
{
    extern __shared__ u16 sm[];
    const int bh = blockIdx.x, t = threadIdx.x;
    {   // ---- K ----
        const u16* src = Kb + (size_t)bh * 25600;
        for (int c = t; c < 3200; c += 256) {
            const int d = c / 50, k8 = (c % 50) * 8;
            *(s8v*)(sm + ((d * 512 + k8) ^ (((d >> 3) & 7) << 3))) =
                *(const s8v*)(src + (size_t)c * 8);
        }
        __syncthreads();
        u16* o = Ktg + (size_t)bh * 25600;
        for (int c = t; c < 3200; c += 256) {
            const int key = c >> 3, d0 = (c & 7) * 8;
            u8v v;
            #pragma unroll
            for (int j = 0; j < 8; ++j) {
                const int d = d0 + j;
                v[j] = sm[(d * 512 + key) ^ (((d >> 3) & 7) << 3)];
            }
            *(u8v*)(o + key * 64 + d0) = v;
        }
    }
    __syncthreads();
    {   // ---- V ----
        const u16* src = Vb + (size_t)bh * 25600;
        for (int c = t; c < 3200; c += 256) {
            const int key = c >> 3, d0 = (c & 7) * 8;
            *(s8v*)(sm + ((key * 64 + d0) ^ (((key >> 3) & 7) << 3))) =
                *(const s8v*)(src + (size_t)c * 8);
        }
        __syncthreads();
        u16* o = Vtg + (size_t)bh * 26624;       // [64][416]
        for (int c = t; c < 3584; c += 256) {
            const int d = ((c >> 3) & 7) + (((c >> 6) & 7) << 3);
            const int s = (c & 7) + ((c >> 9) << 3);
            if (s >= 52) continue;
            const int key0 = s * 8;
            u8v v;
            #pragma unroll
            for (int j = 0; j < 8; ++j) {
                const int key = key0 + j;
                v[j] = (key < 400)
                     ? sm[(key * 64 + d) ^ (((key >> 3) & 7) << 3)] : (u16)0;
            }
            *(u8v*)(o + d * 416 + key0) = v;
        }
    }
}

// ---- attn: one block per (head, 40-query chunk) ---------------------------
// 6400 blocks x 512 thr (8 waves).  LDS: Pb[40][424]u16 + Vl[40][64]f32 +
// rs[40]f32 = 44320B -> 3 blocks/CU.  B5 3-deep ring, B3 5-row batch,
// x prefetched at kernel entry.
#define ATTN_LDS 44320
__global__ __launch_bounds__(512, 6)
void attn(const u16* __restrict__ Qb, const u16* __restrict__ Ktg,
          const u16* __restrict__ Vtg, const float* __restrict__ x,
          const float* __restrict__ gamma, const float* __restrict__ beta,
          float* __restrict__ out)
{
    extern __shared__ char smem[];
    u16*   Pb  = (u16*)smem;               // [40][424]
    float* Vl  = (float*)(smem + 33920);   // [40][64]
    float* rs_ = (float*)(smem + 44160);   // [40]

    const int bx = blockIdx.x;
    const int sw = (bx & 7) * 800 + (bx >> 3);    // XCD swizzle (6400%8==0)
    const int bh = sw / 10, qc = sw % 10;
    const int t = threadIdx.x, lane = t & 63, w = t >> 6;
    const int l15 = lane & 15, quad = lane >> 4;
    const size_t kbase = (size_t)bh * 25600;
    const size_t vbase = (size_t)bh * 26624;
    const size_t qoff0 = kbase + (size_t)qc * 2560;
    const int M0[3] = {0, 16, 24};

    // prefetch x rows for B6 (waves 0-3) -- latency hides under B2..B5
    const size_t grow = ((size_t)bh * 40 + qc * 4 + w) * 640;
    float xpre[10];
    if (w < 4) {
        #pragma unroll
        for (int ci = 0; ci < 10; ++ci) xpre[ci] = x[grow + lane + 64 * ci];
    }

    // B2: scores.  Q frags preloaded once; K frags 2-deep pipelined.
    s8v qf[3][2];
    #pragma unroll
    for (int mt = 0; mt < 3; ++mt)
        #pragma unroll
        for (int kq = 0; kq < 2; ++kq)
            qf[mt][kq] = *(const s8v*)(Qb + qoff0
                         + (size_t)(M0[mt] + l15) * 64 + kq * 32 + quad * 8);

    int nts[4]; int nn = 0;
    for (int nt = w; nt < 25; nt += 8) nts[nn++] = nt;
    s8v k0c, k1c;
    {
        const u16* kp = Ktg + kbase + (size_t)(nts[0] * 16 + l15) * 64 + quad * 8;
        k0c = *(const s8v*)(kp); k1c = *(const s8v*)(kp + 32);
    }
    #pragma unroll
    for (int j = 0; j < 4; ++j) {
        if (j >= nn) break;
        s8v k0n = k0c, k1n = k1c;
        if (j + 1 < nn) {                   // prefetch next K tile
            const u16* kp = Ktg + kbase
                          + (size_t)(nts[j + 1] * 16 + l15) * 64 + quad * 8;
            k0n = *(const s8v*)(kp); k1n = *(const s8v*)(kp + 32);
        }
        const int nt = nts[j];
        #pragma unroll
        for (int mt = 0; mt < 3; ++mt) {
            f4v acc = (f4v){0.f, 0.f, 0.f, 0.f};
            acc = __builtin_amdgcn_mfma_f32_16x16x32_bf16(qf[mt][0], k0c, acc, 0, 0, 0);
            acc = __builtin_amdgcn_mfma_f32_16x16x32_bf16(qf[mt][1], k1c, acc, 0, 0, 0);
            #pragma unroll
            for (int i = 0; i < 4; ++i)
                Pb[(M0[mt] + quad * 4 + i) * 424 + nt * 16 + l15] =
                    f2us(acc[i] * 0.125f);                 // 1/sqrt(64)
        }
        k0c = k0n; k1c = k1n;
    }
    __syncthreads();

    // B3: softmax, all 5 rows of this wave processed concurrently (ILP).
    {
        const int  c0  = lane * 8;             // 0..504
        const bool act = (c0 < 424);
        s8v pv[5];
        #pragma unroll
        for (int r = 0; r < 5; ++r)
            if (act) pv[r] = *(const s8v*)(Pb + (w + r * 8) * 424 + c0);
        float mx[5];
        #pragma unroll
        for (int r = 0; r < 5; ++r) {
            float m = -1e30f;
            if (act) {
                #pragma unroll
                for (int j = 0; j < 8; ++j)
                    if (c0 + j < 400) m = fmaxf(m, us2f((u16)pv[r][j]));
            }
            mx[r] = m;
        }
        #pragma unroll
        for (int off = 32; off; off >>= 1)
            #pragma unroll
            for (int r = 0; r < 5; ++r)
                mx[r] = fmaxf(mx[r], __shfl_xor(mx[r], off));
        float sm5[5];
        #pragma unroll
        for (int r = 0; r < 5; ++r) {
            float s = 0.f;
            if (act) {
                u8v ev;
                #pragma unroll
                for (int j = 0; j < 8; ++j) {
                    const float e = (c0 + j < 400)
                                  ? __expf(us2f((u16)pv[r][j]) - mx[r]) : 0.f;
                    s += e; ev[j] = f2us(e);
                }
                *(u8v*)(Pb + (w + r * 8) * 424 + c0) = ev;
            }
            sm5[r] = s;
        }
        #pragma unroll
        for (int off = 32; off; off >>= 1)
            #pragma unroll
            for (int r = 0; r < 5; ++r)
                sm5[r] += __shfl_xor(sm5[r], off);
        if (lane == 0) {
            #pragma unroll
            for (int r = 0; r < 5; ++r) rs_[w + r * 8] = sm5[r];
        }
    }
    __syncthreads();

    // B5: E @ V, 3-deep static ring.  wave w: nt=w&3; mt {w>>2} (+t2 if w<4)
    {
        const int ntv = w & 3;
        const int mA  = w >> 2;                 // 0 or 1
        const bool two = (mA == 0);             // waves 0-3 also do M0[2]=24
        f4v acc0 = (f4v){0.f, 0.f, 0.f, 0.f};
        f4v acc1 = (f4v){0.f, 0.f, 0.f, 0.f};
        const u16* vp  = Vtg + vbase + (size_t)(ntv * 16 + l15) * 416 + quad * 8;
        const u16* pa  = Pb + (M0[mA] + l15) * 424 + quad * 8;
        const u16* pa2 = Pb + (24 + l15) * 424 + quad * 8;
        s8v vb[3], pb0[3], pb2[3];
        #pragma unroll
        for (int kp = 0; kp < 3; ++kp) {       // preload ring (k=0..2)
            vb[kp]  = *(const s8v*)(vp  + kp * 32);
            pb0[kp] = *(const s8v*)(pa  + kp * 32);
            pb2[kp] = *(const s8v*)(pa2 + kp * 32);
        }
        #pragma unroll
        for (int k = 0; k < 13; ++k) {         // fully unrolled: static ring idx
            const int s = k % 3;
            const s8v b = vb[s], p0 = pb0[s], p2 = pb2[s];
            if (k + 3 < 13) {                  // prefetch 3 ahead
                vb[s]  = *(const s8v*)(vp  + (k + 3) * 32);
                pb0[s] = *(const s8v*)(pa  + (k + 3) * 32);
                pb2[s] = *(const s8v*)(pa2 + (k + 3) * 32);
            }
            acc0 = __builtin_amdgcn_mfma_f32_16x16x32_bf16(p0, b, acc0, 0, 0, 0);
            if (two)
                acc1 = __builtin_amdgcn_mfma_f32_16x16x32_bf16(p2, b, acc1, 0, 0, 0);
        }
        #pragma unroll
        for (int i = 0; i < 4; ++i) {
            Vl[(M0[mA] + quad * 4 + i) * 64 + ntv * 16 + l15] = acc0[i];
            if (two) Vl[(24 + quad * 4 + i) * 64 + ntv * 16 + l15] = acc1[i];
        }
    }
    __syncthreads();

    // B6: 4 output rows; waves 0..3: vals/l + x -> LayerNorm -> out (fp32)
    if (w < 4) {
        float vl[10], rr[10], gv[10], bv[10];
        #pragma unroll
        for (int ci = 0; ci < 10; ++ci) {
            const int col = lane + 64 * ci;
            gv[ci] = gamma[col];
            bv[ci] = beta[col];
            vl[ci] = Vl[w * 640 + col];
            rr[ci] = rs_[w * 10 + ci];
        }
        float y[10], s = 0.f, ss = 0.f;
        #pragma unroll
        for (int ci = 0; ci < 10; ++ci) {
            const float v = vl[ci] / rr[ci] + xpre[ci];
            y[ci] = v; s += v; ss += v * v;
        }
        #pragma unroll
        for (int off = 32; off; off >>= 1) {
            s += __shfl_xor(s, off); ss += __shfl_xor(ss, off);
        }
        const float mu = s * (1.f / 640.f);
        float var = ss * (1.f / 640.f) - mu * mu;
        var = fmaxf(var, 0.f);
        const float rstd = rsqrtf(var + 1e-5f);
        #pragma unroll
        for (int ci = 0; ci < 10; ++ci) {
            const int col = lane + 64 * ci;
            out[grow + col] = (y[ci] - mu) * rstd * gv[ci] + bv[ci];
        }
    }
}

// ======================= OLD FUSED PATH (fallback) =========================
#define LDS_BYTES 163712

template<int MODE>
__global__ __launch_bounds__(1024, 4)
void mha(const float* __restrict__ x,
         const float* __restrict__ Wq, const float* __restrict__ Wk,
         const float* __restrict__ Wv,
         const float* __restrict__ gamma, const float* __restrict__ beta,
         float* __restrict__ out,
         const u16* __restrict__ Wb, u16* __restrict__ Qb)
{
    extern __shared__ char smem[];
    u16*   Kt  = (u16*)(smem);
    u16*   Vt  = (u16*)(smem + 57600);
    u16*   Xs  = (u16*)(smem + 111872);
    u16*   Pb  = (u16*)(smem + 111872);
    float* Vl  = (float*)(smem + 145792);
    float* rs_ = (float*)(smem + 156032);

    const int    bh   = blockIdx.x;
    const size_t base = (size_t)bh * 25600;
    const int    t    = threadIdx.x;
    const int    lane = t & 63;
    const int    w    = t >> 6;
    const int    l15  = lane & 15;
    const int    quad = lane >> 4;

    for (int i = t; i < 6400; i += 1024) {
        const int row = i / 160, col = (i % 160) * 4;
        const float4 v = *(const float4*)(x + base + row * 640 + col);
        *(u4v*)(Xs + row * 648 + col) =
            (u4v){f2us(v.x), f2us(v.y), f2us(v.z), f2us(v.w)};
    }
    for (int i = t; i < 64 * 24; i += 1024)
        Vt[(i / 24) * 424 + 400 + (i % 24)] = 0;
    __syncthreads();

    {
        const int M0a[3] = {0, 16, 24};
        int nts[3], nnt = 0;
        for (int nt = w; nt < 40; nt += 16) nts[nnt++] = nt;

        for (int zi = 0; zi < 3; ++zi) {
            const float* Wsrc = (zi == 0) ? Wq : (zi == 1) ? Wk : Wv;
            f4v acc[3][3];
            #pragma unroll
            for (int a = 0; a < 3; ++a)
                #pragma unroll
                for (int b = 0; b < 3; ++b) acc[a][b] = (f4v){0.f,0.f,0.f,0.f};

            for (int k0 = 0; k0 < 640; k0 += 32) {
                s8v afr[3];
                #pragma unroll
                for (int mt = 0; mt < 3; ++mt)
                    afr[mt] = *(const s8v*)(Xs + (M0a[mt] + l15) * 648 + k0 + quad * 8);
                #pragma unroll
                for (int nk = 0; nk < 3; ++nk) {
                    if (nk >= nnt) break;
                    const int nt = nts[nk];
                    s8v bfr;
                    if (MODE == 0)
                        bfr = *(const s8v*)(Wb + (size_t)zi * 409600
                                            + (nt * 16 + l15) * 640 + k0 + quad * 8);
                    else
                        bfr = ld8f(Wsrc + (size_t)(nt * 16 + l15) * 640 + k0 + quad * 8);
                    #pragma unroll
                    for (int mt = 0; mt < 3; ++mt)
                        acc[nk][mt] = __builtin_amdgcn_mfma_f32_16x16x32_bf16(
                            afr[mt], bfr, acc[nk][mt], 0, 0, 0);
                }
            }
            #pragma unroll
            for (int nk = 0; nk < 3; ++nk) {
                if (nk >= nnt) break;
                #pragma unroll
                for (int mt = 0; mt < 3; ++mt)
                    #pragma unroll
                    for (int i = 0; i < 4; ++i) {
                        const int r  = M0a[mt] + quad * 4 + i;
                        const int oc = nts[nk] * 16 + l15;
                        const int f  = r * 640 + oc;
                        const float v = acc[nk][mt][i];
                        if (zi == 0) {
                            if (MODE == 0) Qb[base + f] = f2us(v);
                            else           out[base + f] = v;
                        } else if (zi == 1) {
                            const int d = f / 400, key = f - d * 400;
                            Kt[key * 72 + d] = f2us(v);
                        } else {
                            Vt[(f & 63) * 424 + (f >> 6)] = f2us(v);
                        }
                    }
            }
        }
    }
    __syncthreads();

    const int M0b[3] = {0, 16, 24};
    for (int qc = 0; qc < 10; ++qc) {
        for (int nt = w; nt < 25; nt += 16) {
            s8v bfr[2];
            #pragma unroll
            for (int kq = 0; kq < 2; ++kq)
                bfr[kq] = *(const s8v*)(Kt + (nt * 16 + l15) * 72 + kq * 32 + quad * 8);
            #pragma unroll
            for (int mt = 0; mt < 3; ++mt) {
                f4v acc = (f4v){0.f, 0.f, 0.f, 0.f};
                #pragma unroll
                for (int kq = 0; kq < 2; ++kq) {
                    const size_t qoff = base + (size_t)qc * 2560
                                      + (M0b[mt] + l15) * 64 + kq * 32 + quad * 8;
                    s8v a = (MODE == 0) ? *(const s8v*)(Qb + qoff) : ld8f(out + qoff);
                    acc = __builtin_amdgcn_mfma_f32_16x16x32_bf16(a, bfr[kq], acc, 0, 0, 0);
                }
                #pragma unroll
                for (int i = 0; i < 4; ++i)
                    Pb[(M0b[mt] + quad * 4 + i) * 424 + nt * 16 + l15] =
                        f2us(acc[i] * 0.125f);
            }
        }
        __syncthreads();

        for (int q = w; q < 40; q += 16) {
            float sv[7], m = -1e30f;
            #pragma unroll
            for (int ii = 0; ii < 7; ++ii) {
                const int c = lane + ii * 64;
                sv[ii] = (c < 400) ? us2f(Pb[q * 424 + c]) : -1e30f;
                m = fmaxf(m, sv[ii]);
            }
            #pragma unroll
            for (int off = 32; off; off >>= 1) m = fmaxf(m, __shfl_xor(m, off));
            float s = 0.f;
            #pragma unroll
            for (int ii = 0; ii < 7; ++ii) {
                const int c = lane + ii * 64;
                const float e = (c < 400) ? __expf(sv[ii] - m) : 0.f;
                s += e;
                if (c < 424) Pb[q * 424 + c] = f2us(e);
            }
            #pragma unroll
            for (int off = 32; off; off >>= 1) s += __shfl_xor(s, off);
            if (lane == 0) rs_[q] = s;
        }
        __syncthreads();

        if (w < 12) {
            const int mt = w >> 2, nt = w & 3;
            f4v acc = (f4v){0.f, 0.f, 0.f, 0.f};
            for (int k0 = 0; k0 < 416; k0 += 32) {
                s8v a = *(const s8v*)(Pb + (M0b[mt] + l15) * 424 + k0 + quad * 8);
                s8v b = *(const s8v*)(Vt + (nt * 16 + l15) * 424 + k0 + quad * 8);
                acc = __builtin_amdgcn_mfma_f32_16x16x32_bf16(a, b, acc, 0, 0, 0);
            }
            #pragma unroll
            for (int i = 0; i < 4; ++i)
                Vl[(M0b[mt] + quad * 4 + i) * 64 + nt * 16 + l15] = acc[i];
        }
        __syncthreads();

        if (w < 4) {
            const int    r    = qc * 4 + w;
            const size_t grow = base + (size_t)r * 640;
            float y[10], s = 0.f, ss = 0.f;
            #pragma unroll
            for (int ci = 0; ci < 10; ++ci) {
                const int col = lane + 64 * ci;
                const float v = Vl[w * 640 + col] / rs_[w * 10 + ci] + x[grow + col];
                y[ci] = v; s += v; ss += v * v;
            }
            #pragma unroll
            for (int off = 32; off; off >>= 1) {
                s += __shfl_xor(s, off); ss += __shfl_xor(ss, off);
            }
            const float mu = s * (1.f / 640.f);
            float var = ss * (1.f / 640.f) - mu * mu;
            var = fmaxf(var, 0.f);
            const float rstd = rsqrtf(var + 1e-5f);
            #pragma unroll
            for (int ci = 0; ci < 10; ++ci) {
                const int col = lane + 64 * ci;
                out[grow + col] = (y[ci] - mu) * rstd * gamma[col] + beta[col];
            }
        }
    }
}

__global__ __launch_bounds__(256)
void wconv(const float* __restrict__ Wq, const float* __restrict__ Wk,
           const float* __restrict__ Wv, u16* __restrict__ Wb)
{
    const int g = blockIdx.x * 256 + threadIdx.x;
    const float* src = (g < 51200) ? Wq : (g < 102400) ? Wk : Wv;
    const int rem = g % 51200;
    *(s8v*)(Wb + (size_t)g * 8) = ld8f(src + (size_t)rem * 8);
}

// ---------------------------------------------------------------------------
extern "C" void kernel_launch(void* const* d_in, const int* in_sizes, int n_in,
                              void* d_out, int out_size, void* d_ws, size_t ws_size,
                              hipStream_t stream)
{
    const float* x     = (const float*)d_in[0];
    const float* Wq    = (const float*)d_in[1];
    const float* Wk    = (const float*)d_in[2];
    const float* Wv    = (const float*)d_in[3];
    const float* gamma = (const float*)d_in[4];
    const float* beta  = (const float*)d_in[5];
    float* out = (float*)d_out;
    (void)in_sizes; (void)n_in; (void)out_size;

    hipFuncSetAttribute(reinterpret_cast<const void*>(&qkv),
                        hipFuncAttributeMaxDynamicSharedMemorySize, QKV_LDS);
    hipFuncSetAttribute(reinterpret_cast<const void*>(&kvt),
                        hipFuncAttributeMaxDynamicSharedMemorySize, 65536);
    hipFuncSetAttribute(reinterpret_cast<const void*>(&attn),
                        hipFuncAttributeMaxDynamicSharedMemorySize, ATTN_LDS);
    hipFuncSetAttribute(reinterpret_cast<const void*>(&mha<0>),
                        hipFuncAttributeMaxDynamicSharedMemorySize, LDS_BYTES);
    hipFuncSetAttribute(reinterpret_cast<const void*>(&mha<1>),
                        hipFuncAttributeMaxDynamicSharedMemorySize, LDS_BYTES);

    // ws layout (u16 units): Wb 1228800 | xb 16384000 | Qb/Kb/Vb/Ktg 16384000
    // each | Vtg 17039360  -> total 200376320 bytes
    const size_t NEED_NEW = 200376320ull;

    if (ws_size >= NEED_NEW) {
        u16* Wb  = (u16*)d_ws;
        u16* xb  = Wb  + 1228800;
        u16* Qb  = xb  + 16384000;
        u16* Kb  = Qb  + 16384000;
        u16* Vb  = Kb  + 16384000;
        u16* Ktg = Vb  + 16384000;
        u16* Vtg = Ktg + 16384000;
        cvt <<<8600, 256, 0, stream>>>(Wq, Wk, Wv, x, Wb, xb);
        qkv <<<3000, 256, QKV_LDS, stream>>>(xb, Wb, Qb, Kb, Vb);
        kvt <<<640,  256, 65536, stream>>>(Kb, Vb, Ktg, Vtg);
        attn<<<6400, 512, ATTN_LDS, stream>>>(Qb, Ktg, Vtg, x, gamma, beta, out);
    } else if (ws_size >= (size_t)(2457600 + 32768000)) {
        u16* Wb = (u16*)d_ws;
        u16* Qb = Wb + 1228800;
        wconv<<<600, 256, 0, stream>>>(Wq, Wk, Wv, Wb);
        mha<0><<<640, 1024, LDS_BYTES, stream>>>(x, Wq, Wk, Wv, gamma, beta, out, Wb, Qb);
    } else {
        mha<1><<<640, 1024, LDS_BYTES, stream>>>(x, Wq, Wk, Wv, gamma, beta, out,
                                                 (const u16*)d_ws, (u16*)d_ws);
    }
}

// Round 5
// 373.584 us; speedup vs baseline: 1.0799x; 1.0799x over previous
//
#include <hip/hip_runtime.h>
#include <hip/hip_bf16.h>

// ---------------------------------------------------------------------------
// Problem: N=25600 rows, D=640, B=64, H=10, dk=64, SEQ=400.  head_splitter is
// a RAW RESHAPE: head (b,h) owns flat range [bh*25600,+25600) == x-rows
// [bh*40,+40) x all 640 cols.  Qblk/Vblk = range viewed [400][64]; Kblk =
// same range viewed [64][400].  vals flat order == out flat order.
//
// R9.  R8 post-mortem: attn 159->220us regression = xpre[10] scratch spill
// (WRITE_SIZE +63.9MB == 256thr x 40B x 6400 blocks exactly; conditional
// array live across barriers -> local memory).  qkv repack epilogue helped
// (~150->~138us).  This round: attn reverted to R7-proven per-wave code,
// but block halved to 20-query chunks: LDS 22.2KB -> 7 blocks/CU (was 3),
// 256 thr, 12800 blocks -> 7 independent barrier chains per CU for latency
// hiding.  M-tiles {0,4} (rows 4..15 dup-written, benign); B5 every wave
// owns one V-tile with both M-tiles.  qkv/cvt/kvt unchanged from R8.
// ---------------------------------------------------------------------------

typedef unsigned short u16;
typedef short s8v __attribute__((ext_vector_type(8)));   // 8 bf16 (4 VGPRs)
typedef float f4v __attribute__((ext_vector_type(4)));   // MFMA accumulator
typedef u16  u4v __attribute__((ext_vector_type(4)));    // 4 bf16 (8B store)
typedef u16  u8v __attribute__((ext_vector_type(8)));    // 8 bf16 (16B store)

__device__ __forceinline__ float us2f(u16 u) {
    union { float f; unsigned int i; } v; v.i = ((unsigned int)u) << 16; return v.f;
}
__device__ __forceinline__ u16 f2us(float f) {
    __hip_bfloat16 h = __float2bfloat16(f);
    return *reinterpret_cast<u16*>(&h);
}
__device__ __forceinline__ s8v ld8f(const float* p) {   // 8 fp32 -> bf16x8
    const float4 a = ((const float4*)p)[0], b = ((const float4*)p)[1];
    s8v r;
    r[0] = (short)f2us(a.x); r[1] = (short)f2us(a.y);
    r[2] = (short)f2us(a.z); r[3] = (short)f2us(a.w);
    r[4] = (short)f2us(b.x); r[5] = (short)f2us(b.y);
    r[6] = (short)f2us(b.z); r[7] = (short)f2us(b.w);
    return r;
}
__device__ __forceinline__ void gload16(const u16* g, u16* l) {
    u16* gm = const_cast<u16*>(g);                       // builtin is non-const
    __builtin_amdgcn_global_load_lds(
        (__attribute__((address_space(1))) unsigned int*)gm,
        (__attribute__((address_space(3))) unsigned int*)l, 16, 0, 0);
}

// ============================ NEW PATH =====================================

// ---- cvt: W (3x640x640) and x (25600x640) fp32 -> bf16 --------------------
__global__ __launch_bounds__(256)
void cvt(const float* __restrict__ Wq, const float* __restrict__ Wk,
         const float* __restrict__ Wv, const float* __restrict__ x,
         u16* __restrict__ Wb, u16* __restrict__ xb)
{
    const int g = blockIdx.x * 256 + threadIdx.x;
    if (g < 153600) {
        const float* src = (g < 51200) ? Wq : (g < 102400) ? Wk : Wv;
        const int rem = g % 51200;
        *(s8v*)(Wb + (size_t)g * 8) = ld8f(src + (size_t)rem * 8);
    } else {
        const int gx = g - 153600;
        *(s8v*)(xb + (size_t)gx * 8) = ld8f(x + (size_t)gx * 8);
    }
}

// ---- qkv: [25600x640]bf16 @ Wb^T[1920x640]bf16 -> Q/K/V bf16 --------------
// 128x128 tile, BK=64, 256 thr (4 waves 2x2, 64x64 each, 4x4 acc).
// Staging via global_load_lds dwordx4, 16B-granule XOR swizzle.  Epilogue
// repacks C through LDS (row stride 144 u16) -> 8 coalesced b128 stores.
// Grid: XCD swizzle then A-panel-major (15 consecutive blocks per x-panel).
#define QKV_LDS 36864
__global__ __launch_bounds__(256, 4)
void qkv(const u16* __restrict__ xb, const u16* __restrict__ Wb,
         u16* __restrict__ Qb, u16* __restrict__ Kb, u16* __restrict__ Vb)
{
    extern __shared__ u16 qsm[];                // 36864 B
    u16* As = qsm;                              // [128][64] swizzled, 16KB
    u16* Bs = qsm + 8192;                       // [128][64] swizzled, 16KB
    const int bx = blockIdx.x;
    const int sw = (bx & 7) * 375 + (bx >> 3);  // XCD swizzle (3000 = 8*375)
    const int mt = sw / 15, nt = sw % 15;       // A-panel-major
    const int m0 = mt * 128, n0 = nt * 128;
    const int t = threadIdx.x, lane = t & 63, w = t >> 6;
    const int l15 = lane & 15, quad = lane >> 4;
    const int wr = w >> 1, wc = w & 1;

    f4v acc[4][4];
    #pragma unroll
    for (int a = 0; a < 4; ++a)
        #pragma unroll
        for (int b = 0; b < 4; ++b) acc[a][b] = (f4v){0.f, 0.f, 0.f, 0.f};

    for (int k0 = 0; k0 < 640; k0 += 64) {
        __syncthreads();                   // prev iter's frag reads done
        #pragma unroll
        for (int j = 0; j < 4; ++j) {
            const int c  = (w * 4 + j) * 64 + lane;      // linear 16B chunk
            const int rg = c >> 3;
            const int sg = (c & 7) ^ (rg & 7);           // inverse swizzle
            gload16(xb + (size_t)(m0 + rg) * 640 + k0 + sg * 8,
                    As + (w * 4 + j) * 512);
            gload16(Wb + (size_t)(n0 + rg) * 640 + k0 + sg * 8,
                    Bs + (w * 4 + j) * 512);
        }
        __syncthreads();                   // vmcnt(0) drained before barrier

        #pragma unroll
        for (int kk = 0; kk < 2; ++kk) {
            s8v af[4], bf[4];
            #pragma unroll
            for (int mi = 0; mi < 4; ++mi) {
                const int row = wr * 64 + mi * 16 + l15;
                const int s   = kk * 4 + quad;
                af[mi] = *(const s8v*)(As + ((row * 8 + (s ^ (row & 7))) << 3));
            }
            #pragma unroll
            for (int ni = 0; ni < 4; ++ni) {
                const int row = wc * 64 + ni * 16 + l15;
                const int s   = kk * 4 + quad;
                bf[ni] = *(const s8v*)(Bs + ((row * 8 + (s ^ (row & 7))) << 3));
            }
            #pragma unroll
            for (int mi = 0; mi < 4; ++mi)
                #pragma unroll
                for (int ni = 0; ni < 4; ++ni)
                    acc[mi][ni] = __builtin_amdgcn_mfma_f32_16x16x32_bf16(
                        af[mi], bf[ni], acc[mi][ni], 0, 0, 0);
        }
    }

    // epilogue: repack through LDS (stride 144 u16), then coalesced stores
    __syncthreads();                       // all frag reads done; reuse qsm
    u16* Cs = qsm;                         // [128][144] u16 = 36864 B
    #pragma unroll
    for (int mi = 0; mi < 4; ++mi)
        #pragma unroll
        for (int ni = 0; ni < 4; ++ni)
            #pragma unroll
            for (int i = 0; i < 4; ++i) {
                const int row = wr * 64 + mi * 16 + quad * 4 + i;
                const int col = wc * 64 + ni * 16 + l15;
                Cs[row * 144 + col] = f2us(acc[mi][ni][i]);
            }
    __syncthreads();
    const int mat = (n0 >= 1280) ? 2 : (n0 >= 640 ? 1 : 0);
    u16* dst = (mat == 0) ? Qb : (mat == 1 ? Kb : Vb);
    const int lc0 = n0 - mat * 640;
    #pragma unroll
    for (int j2 = 0; j2 < 8; ++j2) {
        const int cl  = t + 256 * j2;      // 0..2047 output 16B chunks
        const int row = cl >> 4, cg = cl & 15;
        const s8v v = *(const s8v*)(Cs + row * 144 + cg * 8);
        *(s8v*)(dst + (size_t)(m0 + row) * 640 + lc0 + cg * 8) = v;
    }
}

// ---- kvt: per-head transposes (640 blocks, one head each) -----------------
__global__ __launch_bounds__(256)
void kvt(const u16* __restrict__ Kb, const u16* __restrict__ Vb,
         u16* __restrict__ Ktg, u16* __restrict__ Vtg)
{
    extern __shared__ u16 sm[];
    const int bh = blockIdx.x, t = threadIdx.x;
    {   // ---- K ----
        const u16* src = Kb + (size_t)bh * 25600;
        for (int c = t; c < 3200; c += 256) {
            const int d = c / 50, k8 = (c % 50) * 8;
            *(s8v*)(sm + ((d * 512 + k8) ^ (((d >> 3) & 7) << 3))) =
                *(const s8v*)(src + (size_t)c * 8);
        }
        __syncthreads();
        u16* o = Ktg + (size_t)bh * 25600;
        for (int c = t; c < 3200; c += 256) {
            const int key = c >> 3, d0 = (c & 7) * 8;
            u8v v;
            #pragma unroll
            for (int j = 0; j < 8; ++j) {
                const int d = d0 + j;
                v[j] = sm[(d * 512 + key) ^ (((d >> 3) & 7) << 3)];
            }
            *(u8v*)(o + key * 64 + d0) = v;
        }
    }
    __syncthreads();
    {   // ---- V ----
        const u16* src = Vb + (size_t)bh * 25600;
        for (int c = t; c < 3200; c += 256) {
            const int key = c >> 3, d0 = (c & 7) * 8;
            *(s8v*)(sm + ((key * 64 + d0) ^ (((key >> 3) & 7) << 3))) =
                *(const s8v*)(src + (size_t)c * 8);
        }
        __syncthreads();
        u16* o = Vtg + (size_t)bh * 26624;       // [64][416]
        for (int c = t; c < 3584; c += 256) {
            const int d = ((c >> 3) & 7) + (((c >> 6) & 7) << 3);
            const int s = (c & 7) + ((c >> 9) << 3);
            if (s >= 52) continue;
            const int key0 = s * 8;
            u8v v;
            #pragma unroll
            for (int j = 0; j < 8; ++j) {
                const int key = key0 + j;
                v[j] = (key < 400)
                     ? sm[(key * 64 + d) ^ (((key >> 3) & 7) << 3)] : (u16)0;
            }
            *(u8v*)(o + d * 416 + key0) = v;
        }
    }
}

// ---- attn: one block per (head, 20-query chunk) ---------------------------
// 12800 blocks x 256 thr (4 waves).  LDS: Pb[20][424]u16 + Vl[20][64]f32 +
// rs[20]f32 = 22160B -> 7 blocks/CU (28 waves).  Per-wave code = R7-proven
// patterns; M-tiles {0,4} (rows 4..15 dup, benign).  B6 late x loads (no
// cross-barrier arrays -> no scratch).
#define ATTN_LDS 22160
__global__ __launch_bounds__(256, 7)
void attn(const u16* __restrict__ Qb, const u16* __restrict__ Ktg,
          const u16* __restrict__ Vtg, const float* __restrict__ x,
          const float* __restrict__ gamma, const float* __restrict__ beta,
          float* __restrict__ out)
{
    extern __shared__ char smem[];
    u16*   Pb  = (u16*)smem;               // [20][424]
    float* Vl  = (float*)(smem + 16960);   // [20][64]
    float* rs_ = (float*)(smem + 22080);   // [20]

    const int bx = blockIdx.x;
    const int sw = (bx & 7) * 1600 + (bx >> 3);   // XCD swizzle (12800%8==0)
    const int bh = sw / 20, qc = sw % 20;
    const int t = threadIdx.x, lane = t & 63, w = t >> 6;  // w 0..3
    const int l15 = lane & 15, quad = lane >> 4;
    const size_t kbase = (size_t)bh * 25600;
    const size_t vbase = (size_t)bh * 26624;
    const size_t qoff0 = kbase + (size_t)qc * 1280;
    const int M0[2] = {0, 4};

    // B2: scores.  Q frags preloaded once; K frags 2-deep pipelined.
    s8v qf[2][2];
    #pragma unroll
    for (int mt = 0; mt < 2; ++mt)
        #pragma unroll
        for (int kq = 0; kq < 2; ++kq)
            qf[mt][kq] = *(const s8v*)(Qb + qoff0
                         + (size_t)(M0[mt] + l15) * 64 + kq * 32 + quad * 8);

    int nts[7]; int nn = 0;
    for (int nt = w; nt < 25; nt += 4) nts[nn++] = nt;    // 7,6,6,6
    s8v k0c, k1c;
    {
        const u16* kp = Ktg + kbase + (size_t)(nts[0] * 16 + l15) * 64 + quad * 8;
        k0c = *(const s8v*)(kp); k1c = *(const s8v*)(kp + 32);
    }
    #pragma unroll
    for (int j = 0; j < 7; ++j) {
        if (j >= nn) break;
        s8v k0n = k0c, k1n = k1c;
        if (j + 1 < nn) {                   // prefetch next K tile
            const u16* kp = Ktg + kbase
                          + (size_t)(nts[j + 1] * 16 + l15) * 64 + quad * 8;
            k0n = *(const s8v*)(kp); k1n = *(const s8v*)(kp + 32);
        }
        const int nt = nts[j];
        #pragma unroll
        for (int mt = 0; mt < 2; ++mt) {
            f4v acc = (f4v){0.f, 0.f, 0.f, 0.f};
            acc = __builtin_amdgcn_mfma_f32_16x16x32_bf16(qf[mt][0], k0c, acc, 0, 0, 0);
            acc = __builtin_amdgcn_mfma_f32_16x16x32_bf16(qf[mt][1], k1c, acc, 0, 0, 0);
            #pragma unroll
            for (int i = 0; i < 4; ++i)
                Pb[(M0[mt] + quad * 4 + i) * 424 + nt * 16 + l15] =
                    f2us(acc[i] * 0.125f);                 // 1/sqrt(64)
        }
        k0c = k0n; k1c = k1n;
    }
    __syncthreads();

    // B3: softmax rows {w, w+4, ...}; one b128 read + one b128 write per lane
    for (int q = w; q < 20; q += 4) {
        const int c0 = lane * 8;
        float sv[8]; float m = -1e30f;
        if (c0 < 424) {
            const s8v pv = *(const s8v*)(Pb + q * 424 + c0);
            #pragma unroll
            for (int j = 0; j < 8; ++j) {
                sv[j] = (c0 + j < 400) ? us2f((u16)pv[j]) : -1e30f;
                m = fmaxf(m, sv[j]);
            }
        } else {
            #pragma unroll
            for (int j = 0; j < 8; ++j) sv[j] = -1e30f;
        }
        #pragma unroll
        for (int off = 32; off; off >>= 1) m = fmaxf(m, __shfl_xor(m, off));
        float s = 0.f;
        if (c0 < 424) {
            u8v ev;
            #pragma unroll
            for (int j = 0; j < 8; ++j) {
                const float e = (c0 + j < 400) ? __expf(sv[j] - m) : 0.f;
                s += e; ev[j] = f2us(e);
            }
            *(u8v*)(Pb + q * 424 + c0) = ev;
        }
        #pragma unroll
        for (int off = 32; off; off >>= 1) s += __shfl_xor(s, off);
        if (lane == 0) rs_[q] = s;
    }
    __syncthreads();

    // B5: E @ V, 2-deep pipelined.  wave w owns V-tile nt=w, both M-tiles.
    {
        f4v acc0 = (f4v){0.f, 0.f, 0.f, 0.f};
        f4v acc1 = (f4v){0.f, 0.f, 0.f, 0.f};
        const u16* vp  = Vtg + vbase + (size_t)(w * 16 + l15) * 416 + quad * 8;
        const u16* pa  = Pb + (0 + l15) * 424 + quad * 8;
        const u16* pa2 = Pb + (4 + l15) * 424 + quad * 8;
        s8v bc  = *(const s8v*)(vp);
        s8v p0c = *(const s8v*)(pa);
        s8v p2c = *(const s8v*)(pa2);
        #pragma unroll
        for (int k0 = 0; k0 < 416; k0 += 32) {
            s8v bn = bc, p0n = p0c, p2n = p2c;
            if (k0 + 32 < 416) {               // prefetch next fragments
                bn  = *(const s8v*)(vp + k0 + 32);
                p0n = *(const s8v*)(pa + k0 + 32);
                p2n = *(const s8v*)(pa2 + k0 + 32);
            }
            acc0 = __builtin_amdgcn_mfma_f32_16x16x32_bf16(p0c, bc, acc0, 0, 0, 0);
            acc1 = __builtin_amdgcn_mfma_f32_16x16x32_bf16(p2c, bc, acc1, 0, 0, 0);
            bc = bn; p0c = p0n; p2c = p2n;
        }
        #pragma unroll
        for (int i = 0; i < 4; ++i) {
            Vl[(quad * 4 + i) * 64 + w * 16 + l15] = acc0[i];       // rows 0..15
            Vl[(4 + quad * 4 + i) * 64 + w * 16 + l15] = acc1[i];   // rows 4..19
        }
    }
    __syncthreads();

    // B6: 2 output rows; waves 0..1: vals/l + x -> LayerNorm -> out (fp32)
    if (w < 2) {
        const size_t grow = ((size_t)bh * 40 + qc * 2 + w) * 640;
        float xv[10], vl[10], rr[10], gv[10], bv[10];
        #pragma unroll
        for (int ci = 0; ci < 10; ++ci) {       // hoist loads within B6 (ILP)
            const int col = lane + 64 * ci;
            xv[ci] = x[grow + col];
            gv[ci] = gamma[col];
            bv[ci] = beta[col];
            vl[ci] = Vl[w * 640 + col];
            rr[ci] = rs_[w * 10 + ci];
        }
        float y[10], s = 0.f, ss = 0.f;
        #pragma unroll
        for (int ci = 0; ci < 10; ++ci) {
            const float v = vl[ci] / rr[ci] + xv[ci];
            y[ci] = v; s += v; ss += v * v;
        }
        #pragma unroll
        for (int off = 32; off; off >>= 1) {
            s += __shfl_xor(s, off); ss += __shfl_xor(ss, off);
        }
        const float mu = s * (1.f / 640.f);
        float var = ss * (1.f / 640.f) - mu * mu;
        var = fmaxf(var, 0.f);
        const float rstd = rsqrtf(var + 1e-5f);
        #pragma unroll
        for (int ci = 0; ci < 10; ++ci) {
            const int col = lane + 64 * ci;
            out[grow + col] = (y[ci] - mu) * rstd * gv[ci] + bv[ci];
        }
    }
}

// ======================= OLD FUSED PATH (fallback) =========================
#define LDS_BYTES 163712

template<int MODE>
__global__ __launch_bounds__(1024, 4)
void mha(const float* __restrict__ x,
         const float* __restrict__ Wq, const float* __restrict__ Wk,
         const float* __restrict__ Wv,
         const float* __restrict__ gamma, const float* __restrict__ beta,
         float* __restrict__ out,
         const u16* __restrict__ Wb, u16* __restrict__ Qb)
{
    extern __shared__ char smem[];
    u16*   Kt  = (u16*)(smem);
    u16*   Vt  = (u16*)(smem + 57600);
    u16*   Xs  = (u16*)(smem + 111872);
    u16*   Pb  = (u16*)(smem + 111872);
    float* Vl  = (float*)(smem + 145792);
    float* rs_ = (float*)(smem + 156032);

    const int    bh   = blockIdx.x;
    const size_t base = (size_t)bh * 25600;
    const int    t    = threadIdx.x;
    const int    lane = t & 63;
    const int    w    = t >> 6;
    const int    l15  = lane & 15;
    const int    quad = lane >> 4;

    for (int i = t; i < 6400; i += 1024) {
        const int row = i / 160, col = (i % 160) * 4;
        const float4 v = *(const float4*)(x + base + row * 640 + col);
        *(u4v*)(Xs + row * 648 + col) =
            (u4v){f2us(v.x), f2us(v.y), f2us(v.z), f2us(v.w)};
    }
    for (int i = t; i < 64 * 24; i += 1024)
        Vt[(i / 24) * 424 + 400 + (i % 24)] = 0;
    __syncthreads();

    {
        const int M0a[3] = {0, 16, 24};
        int nts[3], nnt = 0;
        for (int nt = w; nt < 40; nt += 16) nts[nnt++] = nt;

        for (int zi = 0; zi < 3; ++zi) {
            const float* Wsrc = (zi == 0) ? Wq : (zi == 1) ? Wk : Wv;
            f4v acc[3][3];
            #pragma unroll
            for (int a = 0; a < 3; ++a)
                #pragma unroll
                for (int b = 0; b < 3; ++b) acc[a][b] = (f4v){0.f,0.f,0.f,0.f};

            for (int k0 = 0; k0 < 640; k0 += 32) {
                s8v afr[3];
                #pragma unroll
                for (int mt = 0; mt < 3; ++mt)
                    afr[mt] = *(const s8v*)(Xs + (M0a[mt] + l15) * 648 + k0 + quad * 8);
                #pragma unroll
                for (int nk = 0; nk < 3; ++nk) {
                    if (nk >= nnt) break;
                    const int nt = nts[nk];
                    s8v bfr;
                    if (MODE == 0)
                        bfr = *(const s8v*)(Wb + (size_t)zi * 409600
                                            + (nt * 16 + l15) * 640 + k0 + quad * 8);
                    else
                        bfr = ld8f(Wsrc + (size_t)(nt * 16 + l15) * 640 + k0 + quad * 8);
                    #pragma unroll
                    for (int mt = 0; mt < 3; ++mt)
                        acc[nk][mt] = __builtin_amdgcn_mfma_f32_16x16x32_bf16(
                            afr[mt], bfr, acc[nk][mt], 0, 0, 0);
                }
            }
            #pragma unroll
            for (int nk = 0; nk < 3; ++nk) {
                if (nk >= nnt) break;
                #pragma unroll
                for (int mt = 0; mt < 3; ++mt)
                    #pragma unroll
                    for (int i = 0; i < 4; ++i) {
                        const int r  = M0a[mt] + quad * 4 + i;
                        const int oc = nts[nk] * 16 + l15;
                        const int f  = r * 640 + oc;
                        const float v = acc[nk][mt][i];
                        if (zi == 0) {
                            if (MODE == 0) Qb[base + f] = f2us(v);
                            else           out[base + f] = v;
                        } else if (zi == 1) {
                            const int d = f / 400, key = f - d * 400;
                            Kt[key * 72 + d] = f2us(v);
                        } else {
                            Vt[(f & 63) * 424 + (f >> 6)] = f2us(v);
                        }
                    }
            }
        }
    }
    __syncthreads();

    const int M0b[3] = {0, 16, 24};
    for (int qc = 0; qc < 10; ++qc) {
        for (int nt = w; nt < 25; nt += 16) {
            s8v bfr[2];
            #pragma unroll
            for (int kq = 0; kq < 2; ++kq)
                bfr[kq] = *(const s8v*)(Kt + (nt * 16 + l15) * 72 + kq * 32 + quad * 8);
            #pragma unroll
            for (int mt = 0; mt < 3; ++mt) {
                f4v acc = (f4v){0.f, 0.f, 0.f, 0.f};
                #pragma unroll
                for (int kq = 0; kq < 2; ++kq) {
                    const size_t qoff = base + (size_t)qc * 2560
                                      + (M0b[mt] + l15) * 64 + kq * 32 + quad * 8;
                    s8v a = (MODE == 0) ? *(const s8v*)(Qb + qoff) : ld8f(out + qoff);
                    acc = __builtin_amdgcn_mfma_f32_16x16x32_bf16(a, bfr[kq], acc, 0, 0, 0);
                }
                #pragma unroll
                for (int i = 0; i < 4; ++i)
                    Pb[(M0b[mt] + quad * 4 + i) * 424 + nt * 16 + l15] =
                        f2us(acc[i] * 0.125f);
            }
        }
        __syncthreads();

        for (int q = w; q < 40; q += 16) {
            float sv[7], m = -1e30f;
            #pragma unroll
            for (int ii = 0; ii < 7; ++ii) {
                const int c = lane + ii * 64;
                sv[ii] = (c < 400) ? us2f(Pb[q * 424 + c]) : -1e30f;
                m = fmaxf(m, sv[ii]);
            }
            #pragma unroll
            for (int off = 32; off; off >>= 1) m = fmaxf(m, __shfl_xor(m, off));
            float s = 0.f;
            #pragma unroll
            for (int ii = 0; ii < 7; ++ii) {
                const int c = lane + ii * 64;
                const float e = (c < 400) ? __expf(sv[ii] - m) : 0.f;
                s += e;
                if (c < 424) Pb[q * 424 + c] = f2us(e);
            }
            #pragma unroll
            for (int off = 32; off; off >>= 1) s += __shfl_xor(s, off);
            if (lane == 0) rs_[q] = s;
        }
        __syncthreads();

        if (w < 12) {
            const int mt = w >> 2, nt = w & 3;
            f4v acc = (f4v){0.f, 0.f, 0.f, 0.f};
            for (int k0 = 0; k0 < 416; k0 += 32) {
                s8v a = *(const s8v*)(Pb + (M0b[mt] + l15) * 424 + k0 + quad * 8);
                s8v b = *(const s8v*)(Vt + (nt * 16 + l15) * 424 + k0 + quad * 8);
                acc = __builtin_amdgcn_mfma_f32_16x16x32_bf16(a, b, acc, 0, 0, 0);
            }
            #pragma unroll
            for (int i = 0; i < 4; ++i)
                Vl[(M0b[mt] + quad * 4 + i) * 64 + nt * 16 + l15] = acc[i];
        }
        __syncthreads();

        if (w < 4) {
            const int    r    = qc * 4 + w;
            const size_t grow = base + (size_t)r * 640;
            float y[10], s = 0.f, ss = 0.f;
            #pragma unroll
            for (int ci = 0; ci < 10; ++ci) {
                const int col = lane + 64 * ci;
                const float v = Vl[w * 640 + col] / rs_[w * 10 + ci] + x[grow + col];
                y[ci] = v; s += v; ss += v * v;
            }
            #pragma unroll
            for (int off = 32; off; off >>= 1) {
                s += __shfl_xor(s, off); ss += __shfl_xor(ss, off);
            }
            const float mu = s * (1.f / 640.f);
            float var = ss * (1.f / 640.f) - mu * mu;
            var = fmaxf(var, 0.f);
            const float rstd = rsqrtf(var + 1e-5f);
            #pragma unroll
            for (int ci = 0; ci < 10; ++ci) {
                const int col = lane + 64 * ci;
                out[grow + col] = (y[ci] - mu) * rstd * gamma[col] + beta[col];
            }
        }
    }
}

__global__ __launch_bounds__(256)
void wconv(const float* __restrict__ Wq, const float* __restrict__ Wk,
           const float* __restrict__ Wv, u16* __restrict__ Wb)
{
    const int g = blockIdx.x * 256 + threadIdx.x;
    const float* src = (g < 51200) ? Wq : (g < 102400) ? Wk : Wv;
    const int rem = g % 51200;
    *(s8v*)(Wb + (size_t)g * 8) = ld8f(src + (size_t)rem * 8);
}

// ---------------------------------------------------------------------------
extern "C" void kernel_launch(void* const* d_in, const int* in_sizes, int n_in,
                              void* d_out, int out_size, void* d_ws, size_t ws_size,
                              hipStream_t stream)
{
    const float* x     = (const float*)d_in[0];
    const float* Wq    = (const float*)d_in[1];
    const float* Wk    = (const float*)d_in[2];
    const float* Wv    = (const float*)d_in[3];
    const float* gamma = (const float*)d_in[4];
    const float* beta  = (const float*)d_in[5];
    float* out = (float*)d_out;
    (void)in_sizes; (void)n_in; (void)out_size;

    hipFuncSetAttribute(reinterpret_cast<const void*>(&qkv),
                        hipFuncAttributeMaxDynamicSharedMemorySize, QKV_LDS);
    hipFuncSetAttribute(reinterpret_cast<const void*>(&kvt),
                        hipFuncAttributeMaxDynamicSharedMemorySize, 65536);
    hipFuncSetAttribute(reinterpret_cast<const void*>(&attn),
                        hipFuncAttributeMaxDynamicSharedMemorySize, ATTN_LDS);
    hipFuncSetAttribute(reinterpret_cast<const void*>(&mha<0>),
                        hipFuncAttributeMaxDynamicSharedMemorySize, LDS_BYTES);
    hipFuncSetAttribute(reinterpret_cast<const void*>(&mha<1>),
                        hipFuncAttributeMaxDynamicSharedMemorySize, LDS_BYTES);

    // ws layout (u16 units): Wb 1228800 | xb 16384000 | Qb/Kb/Vb/Ktg 16384000
    // each | Vtg 17039360  -> total 200376320 bytes
    const size_t NEED_NEW = 200376320ull;

    if (ws_size >= NEED_NEW) {
        u16* Wb  = (u16*)d_ws;
        u16* xb  = Wb  + 1228800;
        u16* Qb  = xb  + 16384000;
        u16* Kb  = Qb  + 16384000;
        u16* Vb  = Kb  + 16384000;
        u16* Ktg = Vb  + 16384000;
        u16* Vtg = Ktg + 16384000;
        cvt <<<8600, 256, 0, stream>>>(Wq, Wk, Wv, x, Wb, xb);
        qkv <<<3000, 256, QKV_LDS, stream>>>(xb, Wb, Qb, Kb, Vb);
        kvt <<<640,  256, 65536, stream>>>(Kb, Vb, Ktg, Vtg);
        attn<<<12800, 256, ATTN_LDS, stream>>>(Qb, Ktg, Vtg, x, gamma, beta, out);
    } else if (ws_size >= (size_t)(2457600 + 32768000)) {
        u16* Wb = (u16*)d_ws;
        u16* Qb = Wb + 1228800;
        wconv<<<600, 256, 0, stream>>>(Wq, Wk, Wv, Wb);
        mha<0><<<640, 1024, LDS_BYTES, stream>>>(x, Wq, Wk, Wv, gamma, beta, out, Wb, Qb);
    } else {
        mha<1><<<640, 1024, LDS_BYTES, stream>>>(x, Wq, Wk, Wv, gamma, beta, out,
                                                 (const u16*)d_ws, (u16*)d_ws);
    }
}

// Round 7
// 349.567 us; speedup vs baseline: 1.1541x; 1.0687x over previous
//
#include <hip/hip_runtime.h>
#include <hip/hip_bf16.h>

// ---------------------------------------------------------------------------
// Problem: N=25600 rows, D=640, B=64, H=10, dk=64, SEQ=400.  head_splitter is
// a RAW RESHAPE: head (b,h) owns flat range [bh*25600,+25600) == x-rows
// [bh*40,+40) x all 640 cols.  Qblk/Vblk = range viewed [400][64]; Kblk =
// same range viewed [64][400].  vals flat order == out flat order.
//
// R11 = R10 resubmit (R10 died with "container failed twice"; diff vs the
// R5-passing kernel is plain arithmetic only -- swapped-operand MFMA,
// no-max exp, packed stores -- all re-audited in-bounds/aligned; harness
// push times of 957s/1241s in R3/R4 point to infra flake).  Design:
//   attn (VALU-cut, on R7 512-thr/40-query shape):
//   - no-max softmax (scores std ~0.33 -> exp<=~20, exact identity)
//   - swapped QK^T: mfma(K,Q) -> lane holds 4 consecutive KEYS -> packed
//     8B Pb writes; exp fused into B2 epilogue
//   - B3 = sum-only pass (zeroes pad cols 400..423)
//   - rs_ stores 1/sum -> B6 divides become FMAs
// qkv/cvt/kvt unchanged (qkv repack epilogue + gload16 proven R8/R9).
// ---------------------------------------------------------------------------

typedef unsigned short u16;
typedef short s8v __attribute__((ext_vector_type(8)));   // 8 bf16 (4 VGPRs)
typedef float f4v __attribute__((ext_vector_type(4)));   // MFMA accumulator
typedef u16  u4v __attribute__((ext_vector_type(4)));    // 4 bf16 (8B store)
typedef u16  u8v __attribute__((ext_vector_type(8)));    // 8 bf16 (16B store)

__device__ __forceinline__ float us2f(u16 u) {
    union { float f; unsigned int i; } v; v.i = ((unsigned int)u) << 16; return v.f;
}
__device__ __forceinline__ u16 f2us(float f) {
    __hip_bfloat16 h = __float2bfloat16(f);
    return *reinterpret_cast<u16*>(&h);
}
__device__ __forceinline__ s8v ld8f(const float* p) {   // 8 fp32 -> bf16x8
    const float4 a = ((const float4*)p)[0], b = ((const float4*)p)[1];
    s8v r;
    r[0] = (short)f2us(a.x); r[1] = (short)f2us(a.y);
    r[2] = (short)f2us(a.z); r[3] = (short)f2us(a.w);
    r[4] = (short)f2us(b.x); r[5] = (short)f2us(b.y);
    r[6] = (short)f2us(b.z); r[7] = (short)f2us(b.w);
    return r;
}
__device__ __forceinline__ void gload16(const u16* g, u16* l) {
    u16* gm = const_cast<u16*>(g);                       // builtin is non-const
    __builtin_amdgcn_global_load_lds(
        (__attribute__((address_space(1))) unsigned int*)gm,
        (__attribute__((address_space(3))) unsigned int*)l, 16, 0, 0);
}

// ============================ NEW PATH =====================================

// ---- cvt: W (3x640x640) and x (25600x640) fp32 -> bf16 --------------------
__global__ __launch_bounds__(256)
void cvt(const float* __restrict__ Wq, const float* __restrict__ Wk,
         const float* __restrict__ Wv, const float* __restrict__ x,
         u16* __restrict__ Wb, u16* __restrict__ xb)
{
    const int g = blockIdx.x * 256 + threadIdx.x;
    if (g < 153600) {
        const float* src = (g < 51200) ? Wq : (g < 102400) ? Wk : Wv;
        const int rem = g % 51200;
        *(s8v*)(Wb + (size_t)g * 8) = ld8f(src + (size_t)rem * 8);
    } else {
        const int gx = g - 153600;
        *(s8v*)(xb + (size_t)gx * 8) = ld8f(x + (size_t)gx * 8);
    }
}

// ---- qkv: [25600x640]bf16 @ Wb^T[1920x640]bf16 -> Q/K/V bf16 --------------
// 128x128 tile, BK=64, 256 thr (4 waves 2x2, 64x64 each, 4x4 acc).
// Staging via global_load_lds dwordx4, 16B-granule XOR swizzle.  Epilogue
// repacks C through LDS (row stride 144 u16) -> 8 coalesced b128 stores.
// Grid: XCD swizzle then A-panel-major (15 consecutive blocks per x-panel).
#define QKV_LDS 36864
__global__ __launch_bounds__(256, 4)
void qkv(const u16* __restrict__ xb, const u16* __restrict__ Wb,
         u16* __restrict__ Qb, u16* __restrict__ Kb, u16* __restrict__ Vb)
{
    extern __shared__ u16 qsm[];                // 36864 B
    u16* As = qsm;                              // [128][64] swizzled, 16KB
    u16* Bs = qsm + 8192;                       // [128][64] swizzled, 16KB
    const int bx = blockIdx.x;
    const int sw = (bx & 7) * 375 + (bx >> 3);  // XCD swizzle (3000 = 8*375)
    const int mt = sw / 15, nt = sw % 15;       // A-panel-major
    const int m0 = mt * 128, n0 = nt * 128;
    const int t = threadIdx.x, lane = t & 63, w = t >> 6;
    const int l15 = lane & 15, quad = lane >> 4;
    const int wr = w >> 1, wc = w & 1;

    f4v acc[4][4];
    #pragma unroll
    for (int a = 0; a < 4; ++a)
        #pragma unroll
        for (int b = 0; b < 4; ++b) acc[a][b] = (f4v){0.f, 0.f, 0.f, 0.f};

    for (int k0 = 0; k0 < 640; k0 += 64) {
        __syncthreads();                   // prev iter's frag reads done
        #pragma unroll
        for (int j = 0; j < 4; ++j) {
            const int c  = (w * 4 + j) * 64 + lane;      // linear 16B chunk
            const int rg = c >> 3;
            const int sg = (c & 7) ^ (rg & 7);           // inverse swizzle
            gload16(xb + (size_t)(m0 + rg) * 640 + k0 + sg * 8,
                    As + (w * 4 + j) * 512);
            gload16(Wb + (size_t)(n0 + rg) * 640 + k0 + sg * 8,
                    Bs + (w * 4 + j) * 512);
        }
        __syncthreads();                   // vmcnt(0) drained before barrier

        #pragma unroll
        for (int kk = 0; kk < 2; ++kk) {
            s8v af[4], bf[4];
            #pragma unroll
            for (int mi = 0; mi < 4; ++mi) {
                const int row = wr * 64 + mi * 16 + l15;
                const int s   = kk * 4 + quad;
                af[mi] = *(const s8v*)(As + ((row * 8 + (s ^ (row & 7))) << 3));
            }
            #pragma unroll
            for (int ni = 0; ni < 4; ++ni) {
                const int row = wc * 64 + ni * 16 + l15;
                const int s   = kk * 4 + quad;
                bf[ni] = *(const s8v*)(Bs + ((row * 8 + (s ^ (row & 7))) << 3));
            }
            #pragma unroll
            for (int mi = 0; mi < 4; ++mi)
                #pragma unroll
                for (int ni = 0; ni < 4; ++ni)
                    acc[mi][ni] = __builtin_amdgcn_mfma_f32_16x16x32_bf16(
                        af[mi], bf[ni], acc[mi][ni], 0, 0, 0);
        }
    }

    // epilogue: repack through LDS (stride 144 u16), then coalesced stores
    __syncthreads();                       // all frag reads done; reuse qsm
    u16* Cs = qsm;                         // [128][144] u16 = 36864 B
    #pragma unroll
    for (int mi = 0; mi < 4; ++mi)
        #pragma unroll
        for (int ni = 0; ni < 4; ++ni)
            #pragma unroll
            for (int i = 0; i < 4; ++i) {
                const int row = wr * 64 + mi * 16 + quad * 4 + i;
                const int col = wc * 64 + ni * 16 + l15;
                Cs[row * 144 + col] = f2us(acc[mi][ni][i]);
            }
    __syncthreads();
    const int mat = (n0 >= 1280) ? 2 : (n0 >= 640 ? 1 : 0);
    u16* dst = (mat == 0) ? Qb : (mat == 1 ? Kb : Vb);
    const int lc0 = n0 - mat * 640;
    #pragma unroll
    for (int j2 = 0; j2 < 8; ++j2) {
        const int cl  = t + 256 * j2;      // 0..2047 output 16B chunks
        const int row = cl >> 4, cg = cl & 15;
        const s8v v = *(const s8v*)(Cs + row * 144 + cg * 8);
        *(s8v*)(dst + (size_t)(m0 + row) * 640 + lc0 + cg * 8) = v;
    }
}

// ---- kvt: per-head transposes (640 blocks, one head each) -----------------
__global__ __launch_bounds__(256)
void kvt(const u16* __restrict__ Kb, const u16* __restrict__ Vb,
         u16* __restrict__ Ktg, u16* __restrict__ Vtg)
{
    extern __shared__ u16 sm[];
    const int bh = blockIdx.x, t = threadIdx.x;
    {   // ---- K ----
        const u16* src = Kb + (size_t)bh * 25600;
        for (int c = t; c < 3200; c += 256) {
            const int d = c / 50, k8 = (c % 50) * 8;
            *(s8v*)(sm + ((d * 512 + k8) ^ (((d >> 3) & 7) << 3))) =
                *(const s8v*)(src + (size_t)c * 8);
        }
        __syncthreads();
        u16* o = Ktg + (size_t)bh * 25600;
        for (int c = t; c < 3200; c += 256) {
            const int key = c >> 3, d0 = (c & 7) * 8;
            u8v v;
            #pragma unroll
            for (int j = 0; j < 8; ++j) {
                const int d = d0 + j;
                v[j] = sm[(d * 512 + key) ^ (((d >> 3) & 7) << 3)];
            }
            *(u8v*)(o + key * 64 + d0) = v;
        }
    }
    __syncthreads();
    {   // ---- V ----
        const u16* src = Vb + (size_t)bh * 25600;
        for (int c = t; c < 3200; c += 256) {
            const int key = c >> 3, d0 = (c & 7) * 8;
            *(s8v*)(sm + ((key * 64 + d0) ^ (((key >> 3) & 7) << 3))) =
                *(const s8v*)(src + (size_t)c * 8);
        }
        __syncthreads();
        u16* o = Vtg + (size_t)bh * 26624;       // [64][416]
        for (int c = t; c < 3584; c += 256) {
            const int d = ((c >> 3) & 7) + (((c >> 6) & 7) << 3);
            const int s = (c & 7) + ((c >> 9) << 3);
            if (s >= 52) continue;
            const int key0 = s * 8;
            u8v v;
            #pragma unroll
            for (int j = 0; j < 8; ++j) {
                const int key = key0 + j;
                v[j] = (key < 400)
                     ? sm[(key * 64 + d) ^ (((key >> 3) & 7) << 3)] : (u16)0;
            }
            *(u8v*)(o + d * 416 + key0) = v;
        }
    }
}

// ---- attn: one block per (head, 40-query chunk) ---------------------------
// 6400 blocks x 512 thr (8 waves).  LDS: Pb[40][424]u16 + Vl[40][64]f32 +
// rs[40]f32 = 44320B -> 3 blocks/CU.  Swapped QK^T (mfma(K,Q)) -> packed
// exp'd P writes; no-max softmax; B3 sum-only; rs_ = 1/sum.
#define ATTN_LDS 44320
__global__ __launch_bounds__(512, 6)
void attn(const u16* __restrict__ Qb, const u16* __restrict__ Ktg,
          const u16* __restrict__ Vtg, const float* __restrict__ x,
          const float* __restrict__ gamma, const float* __restrict__ beta,
          float* __restrict__ out)
{
    extern __shared__ char smem[];
    u16*   Pb  = (u16*)smem;               // [40][424]
    float* Vl  = (float*)(smem + 33920);   // [40][64]
    float* rs_ = (float*)(smem + 44160);   // [40]

    const int bx = blockIdx.x;
    const int sw = (bx & 7) * 800 + (bx >> 3);    // XCD swizzle (6400%8==0)
    const int bh = sw / 10, qc = sw % 10;
    const int t = threadIdx.x, lane = t & 63, w = t >> 6;
    const int l15 = lane & 15, quad = lane >> 4;
    const size_t kbase = (size_t)bh * 25600;
    const size_t vbase = (size_t)bh * 26624;
    const size_t qoff0 = kbase + (size_t)qc * 2560;
    const int M0[3] = {0, 16, 24};

    // B2: scores.  Q frags (B operand) preloaded once; K frags (A operand)
    // 2-deep pipelined.  mfma(K,Q) -> D[key][query]: lane holds 4 consecutive
    // keys for query l15 -> packed u4v write of exp'd bf16 (no-max softmax).
    s8v qf[3][2];
    #pragma unroll
    for (int mt = 0; mt < 3; ++mt)
        #pragma unroll
        for (int kq = 0; kq < 2; ++kq)
            qf[mt][kq] = *(const s8v*)(Qb + qoff0
                         + (size_t)(M0[mt] + l15) * 64 + kq * 32 + quad * 8);

    int nts[4]; int nn = 0;
    for (int nt = w; nt < 25; nt += 8) nts[nn++] = nt;
    s8v k0c, k1c;
    {
        const u16* kp = Ktg + kbase + (size_t)(nts[0] * 16 + l15) * 64 + quad * 8;
        k0c = *(const s8v*)(kp); k1c = *(const s8v*)(kp + 32);
    }
    #pragma unroll
    for (int j = 0; j < 4; ++j) {
        if (j >= nn) break;
        s8v k0n = k0c, k1n = k1c;
        if (j + 1 < nn) {                   // prefetch next K tile
            const u16* kp = Ktg + kbase
                          + (size_t)(nts[j + 1] * 16 + l15) * 64 + quad * 8;
            k0n = *(const s8v*)(kp); k1n = *(const s8v*)(kp + 32);
        }
        const int nt = nts[j];
        #pragma unroll
        for (int mt = 0; mt < 3; ++mt) {
            f4v acc = (f4v){0.f, 0.f, 0.f, 0.f};
            acc = __builtin_amdgcn_mfma_f32_16x16x32_bf16(k0c, qf[mt][0], acc, 0, 0, 0);
            acc = __builtin_amdgcn_mfma_f32_16x16x32_bf16(k1c, qf[mt][1], acc, 0, 0, 0);
            u4v pv;
            #pragma unroll
            for (int i = 0; i < 4; ++i)
                pv[i] = f2us(__expf(acc[i] * 0.125f));     // 1/sqrt(64), no max
            *(u4v*)(Pb + (M0[mt] + l15) * 424 + nt * 16 + quad * 4) = pv;
        }
        k0c = k0n; k1c = k1n;
    }
    __syncthreads();

    // B3: sum-only pass; rows {w, w+8, ...}.  Zero pad cols 400..423.
    for (int q = w; q < 40; q += 8) {
        const int c0 = lane * 8;
        float s = 0.f;
        if (c0 < 400) {                     // lane<=49: c0+7 <= 399, no guard
            const s8v pvv = *(const s8v*)(Pb + q * 424 + c0);
            #pragma unroll
            for (int j = 0; j < 8; ++j) s += us2f((u16)pvv[j]);
        } else if (c0 < 424) {              // lanes 50..52: zero the pad
            *(u8v*)(Pb + q * 424 + c0) = (u8v){0,0,0,0,0,0,0,0};
        }
        #pragma unroll
        for (int off = 32; off; off >>= 1) s += __shfl_xor(s, off);
        if (lane == 0) rs_[q] = 1.0f / s;   // reciprocal: B6 multiplies
    }
    __syncthreads();

    // B5: E @ V, 2-deep pipelined.  wave w: nt=w&3; mt {w>>2} (+tile2 if w<4)
    {
        const int ntv = w & 3;
        const int mA  = w >> 2;                 // 0 or 1
        const bool two = (mA == 0);             // waves 0-3 also do M0[2]=24
        f4v acc0 = (f4v){0.f, 0.f, 0.f, 0.f};
        f4v acc1 = (f4v){0.f, 0.f, 0.f, 0.f};
        const u16* vp  = Vtg + vbase + (size_t)(ntv * 16 + l15) * 416 + quad * 8;
        const u16* pa  = Pb + (M0[mA] + l15) * 424 + quad * 8;
        const u16* pa2 = Pb + (24 + l15) * 424 + quad * 8;
        s8v bc  = *(const s8v*)(vp);
        s8v p0c = *(const s8v*)(pa);
        s8v p2c = two ? *(const s8v*)(pa2) : p0c;
        #pragma unroll
        for (int k0 = 0; k0 < 416; k0 += 32) {
            s8v bn = bc, p0n = p0c, p2n = p2c;
            if (k0 + 32 < 416) {               // prefetch next fragments
                bn  = *(const s8v*)(vp + k0 + 32);
                p0n = *(const s8v*)(pa + k0 + 32);
                if (two) p2n = *(const s8v*)(pa2 + k0 + 32);
            }
            acc0 = __builtin_amdgcn_mfma_f32_16x16x32_bf16(p0c, bc, acc0, 0, 0, 0);
            if (two)
                acc1 = __builtin_amdgcn_mfma_f32_16x16x32_bf16(p2c, bc, acc1, 0, 0, 0);
            bc = bn; p0c = p0n; p2c = p2n;
        }
        #pragma unroll
        for (int i = 0; i < 4; ++i) {
            Vl[(M0[mA] + quad * 4 + i) * 64 + ntv * 16 + l15] = acc0[i];
            if (two) Vl[(24 + quad * 4 + i) * 64 + ntv * 16 + l15] = acc1[i];
        }
    }
    __syncthreads();

    // B6: 4 output rows; waves 0..3: vals*rinv + x -> LayerNorm -> out (fp32)
    if (w < 4) {
        const size_t grow = ((size_t)bh * 40 + qc * 4 + w) * 640;
        float xv[10], vl[10], rr[10], gv[10], bv[10];
        #pragma unroll
        for (int ci = 0; ci < 10; ++ci) {       // hoist loads within B6 (ILP)
            const int col = lane + 64 * ci;
            xv[ci] = x[grow + col];
            gv[ci] = gamma[col];
            bv[ci] = beta[col];
            vl[ci] = Vl[w * 640 + col];
            rr[ci] = rs_[w * 10 + ci];
        }
        float y[10], s = 0.f, ss = 0.f;
        #pragma unroll
        for (int ci = 0; ci < 10; ++ci) {
            const float v = vl[ci] * rr[ci] + xv[ci];
            y[ci] = v; s += v; ss += v * v;
        }
        #pragma unroll
        for (int off = 32; off; off >>= 1) {
            s += __shfl_xor(s, off); ss += __shfl_xor(ss, off);
        }
        const float mu = s * (1.f / 640.f);
        float var = ss * (1.f / 640.f) - mu * mu;
        var = fmaxf(var, 0.f);
        const float rstd = rsqrtf(var + 1e-5f);
        #pragma unroll
        for (int ci = 0; ci < 10; ++ci) {
            const int col = lane + 64 * ci;
            out[grow + col] = (y[ci] - mu) * rstd * gv[ci] + bv[ci];
        }
    }
}

// ======================= OLD FUSED PATH (fallback) =========================
#define LDS_BYTES 163712

template<int MODE>
__global__ __launch_bounds__(1024, 4)
void mha(const float* __restrict__ x,
         const float* __restrict__ Wq, const float* __restrict__ Wk,
         const float* __restrict__ Wv,
         const float* __restrict__ gamma, const float* __restrict__ beta,
         float* __restrict__ out,
         const u16* __restrict__ Wb, u16* __restrict__ Qb)
{
    extern __shared__ char smem[];
    u16*   Kt  = (u16*)(smem);
    u16*   Vt  = (u16*)(smem + 57600);
    u16*   Xs  = (u16*)(smem + 111872);
    u16*   Pb  = (u16*)(smem + 111872);
    float* Vl  = (float*)(smem + 145792);
    float* rs_ = (float*)(smem + 156032);

    const int    bh   = blockIdx.x;
    const size_t base = (size_t)bh * 25600;
    const int    t    = threadIdx.x;
    const int    lane = t & 63;
    const int    w    = t >> 6;
    const int    l15  = lane & 15;
    const int    quad = lane >> 4;

    for (int i = t; i < 6400; i += 1024) {
        const int row = i / 160, col = (i % 160) * 4;
        const float4 v = *(const float4*)(x + base + row * 640 + col);
        *(u4v*)(Xs + row * 648 + col) =
            (u4v){f2us(v.x), f2us(v.y), f2us(v.z), f2us(v.w)};
    }
    for (int i = t; i < 64 * 24; i += 1024)
        Vt[(i / 24) * 424 + 400 + (i % 24)] = 0;
    __syncthreads();

    {
        const int M0a[3] = {0, 16, 24};
        int nts[3], nnt = 0;
        for (int nt = w; nt < 40; nt += 16) nts[nnt++] = nt;

        for (int zi = 0; zi < 3; ++zi) {
            const float* Wsrc = (zi == 0) ? Wq : (zi == 1) ? Wk : Wv;
            f4v acc[3][3];
            #pragma unroll
            for (int a = 0; a < 3; ++a)
                #pragma unroll
                for (int b = 0; b < 3; ++b) acc[a][b] = (f4v){0.f,0.f,0.f,0.f};

            for (int k0 = 0; k0 < 640; k0 += 32) {
                s8v afr[3];
                #pragma unroll
                for (int mt = 0; mt < 3; ++mt)
                    afr[mt] = *(const s8v*)(Xs + (M0a[mt] + l15) * 648 + k0 + quad * 8);
                #pragma unroll
                for (int nk = 0; nk < 3; ++nk) {
                    if (nk >= nnt) break;
                    const int nt = nts[nk];
                    s8v bfr;
                    if (MODE == 0)
                        bfr = *(const s8v*)(Wb + (size_t)zi * 409600
                                            + (nt * 16 + l15) * 640 + k0 + quad * 8);
                    else
                        bfr = ld8f(Wsrc + (size_t)(nt * 16 + l15) * 640 + k0 + quad * 8);
                    #pragma unroll
                    for (int mt = 0; mt < 3; ++mt)
                        acc[nk][mt] = __builtin_amdgcn_mfma_f32_16x16x32_bf16(
                            afr[mt], bfr, acc[nk][mt], 0, 0, 0);
                }
            }
            #pragma unroll
            for (int nk = 0; nk < 3; ++nk) {
                if (nk >= nnt) break;
                #pragma unroll
                for (int mt = 0; mt < 3; ++mt)
                    #pragma unroll
                    for (int i = 0; i < 4; ++i) {
                        const int r  = M0a[mt] + quad * 4 + i;
                        const int oc = nts[nk] * 16 + l15;
                        const int f  = r * 640 + oc;
                        const float v = acc[nk][mt][i];
                        if (zi == 0) {
                            if (MODE == 0) Qb[base + f] = f2us(v);
                            else           out[base + f] = v;
                        } else if (zi == 1) {
                            const int d = f / 400, key = f - d * 400;
                            Kt[key * 72 + d] = f2us(v);
                        } else {
                            Vt[(f & 63) * 424 + (f >> 6)] = f2us(v);
                        }
                    }
            }
        }
    }
    __syncthreads();

    const int M0b[3] = {0, 16, 24};
    for (int qc = 0; qc < 10; ++qc) {
        for (int nt = w; nt < 25; nt += 16) {
            s8v bfr[2];
            #pragma unroll
            for (int kq = 0; kq < 2; ++kq)
                bfr[kq] = *(const s8v*)(Kt + (nt * 16 + l15) * 72 + kq * 32 + quad * 8);
            #pragma unroll
            for (int mt = 0; mt < 3; ++mt) {
                f4v acc = (f4v){0.f, 0.f, 0.f, 0.f};
                #pragma unroll
                for (int kq = 0; kq < 2; ++kq) {
                    const size_t qoff = base + (size_t)qc * 2560
                                      + (M0b[mt] + l15) * 64 + kq * 32 + quad * 8;
                    s8v a = (MODE == 0) ? *(const s8v*)(Qb + qoff) : ld8f(out + qoff);
                    acc = __builtin_amdgcn_mfma_f32_16x16x32_bf16(a, bfr[kq], acc, 0, 0, 0);
                }
                #pragma unroll
                for (int i = 0; i < 4; ++i)
                    Pb[(M0b[mt] + quad * 4 + i) * 424 + nt * 16 + l15] =
                        f2us(acc[i] * 0.125f);
            }
        }
        __syncthreads();

        for (int q = w; q < 40; q += 16) {
            float sv[7], m = -1e30f;
            #pragma unroll
            for (int ii = 0; ii < 7; ++ii) {
                const int c = lane + ii * 64;
                sv[ii] = (c < 400) ? us2f(Pb[q * 424 + c]) : -1e30f;
                m = fmaxf(m, sv[ii]);
            }
            #pragma unroll
            for (int off = 32; off; off >>= 1) m = fmaxf(m, __shfl_xor(m, off));
            float s = 0.f;
            #pragma unroll
            for (int ii = 0; ii < 7; ++ii) {
                const int c = lane + ii * 64;
                const float e = (c < 400) ? __expf(sv[ii] - m) : 0.f;
                s += e;
                if (c < 424) Pb[q * 424 + c] = f2us(e);
            }
            #pragma unroll
            for (int off = 32; off; off >>= 1) s += __shfl_xor(s, off);
            if (lane == 0) rs_[q] = s;
        }
        __syncthreads();

        if (w < 12) {
            const int mt = w >> 2, nt = w & 3;
            f4v acc = (f4v){0.f, 0.f, 0.f, 0.f};
            for (int k0 = 0; k0 < 416; k0 += 32) {
                s8v a = *(const s8v*)(Pb + (M0b[mt] + l15) * 424 + k0 + quad * 8);
                s8v b = *(const s8v*)(Vt + (nt * 16 + l15) * 424 + k0 + quad * 8);
                acc = __builtin_amdgcn_mfma_f32_16x16x32_bf16(a, b, acc, 0, 0, 0);
            }
            #pragma unroll
            for (int i = 0; i < 4; ++i)
                Vl[(M0b[mt] + quad * 4 + i) * 64 + nt * 16 + l15] = acc[i];
        }
        __syncthreads();

        if (w < 4) {
            const int    r    = qc * 4 + w;
            const size_t grow = base + (size_t)r * 640;
            float y[10], s = 0.f, ss = 0.f;
            #pragma unroll
            for (int ci = 0; ci < 10; ++ci) {
                const int col = lane + 64 * ci;
                const float v = Vl[w * 640 + col] / rs_[w * 10 + ci] + x[grow + col];
                y[ci] = v; s += v; ss += v * v;
            }
            #pragma unroll
            for (int off = 32; off; off >>= 1) {
                s += __shfl_xor(s, off); ss += __shfl_xor(ss, off);
            }
            const float mu = s * (1.f / 640.f);
            float var = ss * (1.f / 640.f) - mu * mu;
            var = fmaxf(var, 0.f);
            const float rstd = rsqrtf(var + 1e-5f);
            #pragma unroll
            for (int ci = 0; ci < 10; ++ci) {
                const int col = lane + 64 * ci;
                out[grow + col] = (y[ci] - mu) * rstd * gamma[col] + beta[col];
            }
        }
    }
}

__global__ __launch_bounds__(256)
void wconv(const float* __restrict__ Wq, const float* __restrict__ Wk,
           const float* __restrict__ Wv, u16* __restrict__ Wb)
{
    const int g = blockIdx.x * 256 + threadIdx.x;
    const float* src = (g < 51200) ? Wq : (g < 102400) ? Wk : Wv;
    const int rem = g % 51200;
    *(s8v*)(Wb + (size_t)g * 8) = ld8f(src + (size_t)rem * 8);
}

// ---------------------------------------------------------------------------
extern "C" void kernel_launch(void* const* d_in, const int* in_sizes, int n_in,
                              void* d_out, int out_size, void* d_ws, size_t ws_size,
                              hipStream_t stream)
{
    const float* x     = (const float*)d_in[0];
    const float* Wq    = (const float*)d_in[1];
    const float* Wk    = (const float*)d_in[2];
    const float* Wv    = (const float*)d_in[3];
    const float* gamma = (const float*)d_in[4];
    const float* beta  = (const float*)d_in[5];
    float* out = (float*)d_out;
    (void)in_sizes; (void)n_in; (void)out_size;

    hipFuncSetAttribute(reinterpret_cast<const void*>(&qkv),
                        hipFuncAttributeMaxDynamicSharedMemorySize, QKV_LDS);
    hipFuncSetAttribute(reinterpret_cast<const void*>(&kvt),
                        hipFuncAttributeMaxDynamicSharedMemorySize, 65536);
    hipFuncSetAttribute(reinterpret_cast<const void*>(&attn),
                        hipFuncAttributeMaxDynamicSharedMemorySize, ATTN_LDS);
    hipFuncSetAttribute(reinterpret_cast<const void*>(&mha<0>),
                        hipFuncAttributeMaxDynamicSharedMemorySize, LDS_BYTES);
    hipFuncSetAttribute(reinterpret_cast<const void*>(&mha<1>),
                        hipFuncAttributeMaxDynamicSharedMemorySize, LDS_BYTES);

    // ws layout (u16 units): Wb 1228800 | xb 16384000 | Qb/Kb/Vb/Ktg 16384000
    // each | Vtg 17039360  -> total 200376320 bytes
    const size_t NEED_NEW = 200376320ull;

    if (ws_size >= NEED_NEW) {
        u16* Wb  = (u16*)d_ws;
        u16* xb  = Wb  + 1228800;
        u16* Qb  = xb  + 16384000;
        u16* Kb  = Qb  + 16384000;
        u16* Vb  = Kb  + 16384000;
        u16* Ktg = Vb  + 16384000;
        u16* Vtg = Ktg + 16384000;
        cvt <<<8600, 256, 0, stream>>>(Wq, Wk, Wv, x, Wb, xb);
        qkv <<<3000, 256, QKV_LDS, stream>>>(xb, Wb, Qb, Kb, Vb);
        kvt <<<640,  256, 65536, stream>>>(Kb, Vb, Ktg, Vtg);
        attn<<<6400, 512, ATTN_LDS, stream>>>(Qb, Ktg, Vtg, x, gamma, beta, out);
    } else if (ws_size >= (size_t)(2457600 + 32768000)) {
        u16* Wb = (u16*)d_ws;
        u16* Qb = Wb + 1228800;
        wconv<<<600, 256, 0, stream>>>(Wq, Wk, Wv, Wb);
        mha<0><<<640, 1024, LDS_BYTES, stream>>>(x, Wq, Wk, Wv, gamma, beta, out, Wb, Qb);
    } else {
        mha<1><<<640, 1024, LDS_BYTES, stream>>>(x, Wq, Wk, Wv, gamma, beta, out,
                                                 (const u16*)d_ws, (u16*)d_ws);
    }
}